// Round 6
// baseline (494.716 us; speedup 1.0000x reference)
//
#include <hip/hip_runtime.h>

#define NB 16
#define TT 8192
#define Bb 4
#define NWG 256      // grid WGs; 1 per CU guaranteed (128KB LDS)

typedef __attribute__((ext_vector_type(8))) short short8;
typedef __attribute__((ext_vector_type(16))) float f32x16;

__device__ __forceinline__ unsigned short bf16_rn(float f) {
  unsigned int u = __float_as_uint(f);
  u += 0x7FFF + ((u >> 16) & 1);
  return (unsigned short)(u >> 16);
}
// within-16-chunk k -> stored position (same permute on both GEMM operands)
__device__ __forceinline__ int kpos(int k) {
  int g = (k >> 2) & 1;
  int e = (k & 3) + 4 * (k >> 3);
  return g * 8 + e;
}
__device__ __forceinline__ int kinv(int p) {
  int g = p >> 3, e = p & 7;
  return (e & 3) + 4 * g + 8 * (e >> 2);
}

// software grid barrier: counters zeroed by hipMemsetAsync before launch
__device__ __forceinline__ void grid_bar(unsigned* cnt, int phase) {
  __syncthreads();                      // drains vmcnt: all global writes issued
  if (threadIdx.x == 0) {
    __threadfence();                    // device-scope release of halo writes
    __hip_atomic_fetch_add(&cnt[phase], 1u, __ATOMIC_RELEASE,
                           __HIP_MEMORY_SCOPE_AGENT);
    while (__hip_atomic_load(&cnt[phase], __ATOMIC_ACQUIRE,
                             __HIP_MEMORY_SCOPE_AGENT) < (unsigned)NWG) {
      __builtin_amdgcn_s_sleep(2);
    }
  }
  __syncthreads();
}

// ---------------------------------------------------------------------------
// All weights fp32 -> bf16, k-permuted. One launch. (validated round 4)
__global__ __launch_bounds__(256) void prep_weights(
    const float* __restrict__ wconv, const float* __restrict__ wres,
    const float* __restrict__ wsk, const float* __restrict__ w1,
    const float* __restrict__ w2, short* __restrict__ dwc,
    short* __restrict__ dwr, short* __restrict__ dws,
    short* __restrict__ dw1, short* __restrict__ dw2)
{
  int i = blockIdx.x * 256 + threadIdx.x;
  if (i < 262144) {
    int k = kinv(i & 15);
    int ic = (i & 48) | k;
    int oc = (i >> 6) & 127;
    int tap = (i >> 13) & 1;
    int blk = i >> 14;
    dwc[i] = (short)bf16_rn(wconv[(((blk * 128 + oc) * 64 + ic) << 1) | tap]);
    return;
  }
  int j = i - 262144;
  if (j < 65536) { dwr[j] = (short)bf16_rn(wres[(j & ~15) | kinv(j & 15)]); return; }
  j -= 65536;
  if (j < 262144) { dws[j] = (short)bf16_rn(wsk[(j & ~15) | kinv(j & 15)]); return; }
  j -= 262144;
  if (j < 65536) { dw1[j] = (short)bf16_rn(w1[(j & ~15) | kinv(j & 15)]); return; }
  j -= 65536;
  if (j < 65536) { dw2[j] = (short)bf16_rn(w2[(j & ~15) | kinv(j & 15)]); return; }
}

// ---------------------------------------------------------------------------
// Fused megakernel: embed + 16 blocks + head. Grid (64,4) = 256 WGs, 512 thr.
// Tile = 128 t-steps. LDS: block {rs 32K | win 32K | zl 16K}; head {y 64K|y2 64K}.
__global__ __launch_bounds__(512, 2) void mega_kernel(
    const int* __restrict__ x, const float* __restrict__ h,
    const float* __restrict__ embed,
    const short* __restrict__ wc, const short* __restrict__ wr,
    const short* __restrict__ wsk, const short* __restrict__ w1,
    const short* __restrict__ w2,
    unsigned short* __restrict__ r16a, unsigned short* __restrict__ r16b,
    unsigned* __restrict__ bar, float* __restrict__ out)
{
  __shared__ __align__(16) char smem[131072];
  float* rs  = (float*)smem;            // [128][64] fp32 resid (persistent)
  short* win = (short*)(smem + 32768);  // [256][64] swizzled conv window
  short* zl  = (short*)(smem + 65536);  // [128][64] swizzled z
  short* yb  = (short*)smem;            // head: [128][256] swizzled (64K)
  short* y2b = (short*)(smem + 65536);  // head: [128][256] swizzled (64K)

  const int b = blockIdx.y;
  const int t0 = blockIdx.x * 128;
  const int tid = threadIdx.x;
  const int lane = tid & 63, wv = tid >> 6;
  const int l31 = lane & 31, hi = lane >> 5;

  // ---- prologue: embed -> rs; publish row 127 (dil[0]=1) ----
  {
    const int* xb = x + b * TT + t0;
#pragma unroll
    for (int it = 0; it < 16; ++it) {
      int u = it * 512 + tid;
      int c = u & 63, t = u >> 6;
      rs[t * 64 + c] = embed[(size_t)xb[t] * 64 + c];
    }
    __syncthreads();
    if (tid < 32) {
      int c0 = tid * 2;
      unsigned int v = (unsigned int)bf16_rn(rs[127 * 64 + c0]) |
                       ((unsigned int)bf16_rn(rs[127 * 64 + c0 + 1]) << 16);
      int p0 = (c0 & 48) | kpos(c0 & 15);
      *(unsigned int*)(r16a + ((size_t)b * TT + t0 + 127) * 64 + p0) = v;
    }
    grid_bar(bar, 0);
  }

  // skip accumulators: D[row=t (4 tiles)][col=sk = wv*32+l31]
  f32x16 s0 = {}, s1 = {}, s2 = {}, s3 = {};
  unsigned short* const bufs[2] = {r16a, r16b};

  for (int i = 0; i < NB; ++i) {
    const int dil = 1 << (i & 7);
    const unsigned short* rbuf = bufs[i & 1];

    // ---- stage halo rows [128-dil,128) from global bf16 ----
    for (int u = tid; u < dil * 8; u += 512) {
      int q = u & 7, w = 128 - dil + (u >> 3);
      int gt = t0 - 128 + w;  // in [t0-dil, t0)
      short8 v = {};
      if (gt >= 0) v = *(const short8*)(rbuf + ((size_t)b * TT + gt) * 64 + q * 8);
      unsigned int byte = (unsigned int)(w * 128 + q * 16) ^ (unsigned int)((w & 7) << 4);
      *(short8*)((char*)win + byte) = v;
    }
    // ---- stage own rows [128,256) from rs (fp32 -> packed bf16) ----
#pragma unroll
    for (int it = 0; it < 8; ++it) {
      int u = it * 512 + tid;  // 128 rows x 32 pairs
      int cpair = u & 31, t = u >> 5;
      int c0 = cpair * 2;
      unsigned int v = (unsigned int)bf16_rn(rs[t * 64 + c0]) |
                       ((unsigned int)bf16_rn(rs[t * 64 + c0 + 1]) << 16);
      int p0 = (c0 & 48) | kpos(c0 & 15);
      int w = t + 128;
      unsigned int byte = (unsigned int)(w * 128 + p0 * 2) ^ (unsigned int)((w & 7) << 4);
      *(unsigned int*)((char*)win + byte) = v;
    }

    // ---- conv acc init from h (fp32 exact) ----
    const int pr = wv >> 2, nt = wv & 3;          // pr: oc-pair group, nt: t tile
    const int tloc = nt * 32 + l31, tcol = t0 + tloc;
    f32x16 aA, aS;
    const float* hb = h + ((size_t)b * 2048 + (size_t)i * 128) * TT;
#pragma unroll
    for (int r = 0; r < 16; ++r) {
      int row = (r & 3) + 4 * hi + 8 * (r >> 2) + 32 * pr;  // 0..63
      aA[r] = hb[(size_t)row * TT + tcol];
      aS[r] = hb[(size_t)(row + 64) * TT + tcol];
    }
    __syncthreads();

    // ---- conv: two K=64 tap GEMMs on the window ----
    const short* wA0 = wc + (size_t)i * 16384 + (32 * pr + l31) * 64;  // tap0
    const short* wA1 = wA0 + 8192;                                     // tap1
    const int r1 = tloc + 128, r0 = tloc + 128 - dil;
#pragma unroll
    for (int ks = 0; ks < 4; ++ks) {
      int off = ks * 16 + 8 * hi;
      short8 b1 = *(const short8*)((char*)win +
          ((unsigned int)(r1 * 128 + off * 2) ^ (unsigned int)((r1 & 7) << 4)));
      short8 b0 = *(const short8*)((char*)win +
          ((unsigned int)(r0 * 128 + off * 2) ^ (unsigned int)((r0 & 7) << 4)));
      short8 a0t = *(const short8*)(wA0 + off);
      short8 a1t = *(const short8*)(wA1 + off);
      short8 a0s = *(const short8*)(wA0 + 4096 + off);
      short8 a1s = *(const short8*)(wA1 + 4096 + off);
      aA = __builtin_amdgcn_mfma_f32_32x32x16_bf16(a0t, b0, aA, 0, 0, 0);
      aA = __builtin_amdgcn_mfma_f32_32x32x16_bf16(a1t, b1, aA, 0, 0, 0);
      aS = __builtin_amdgcn_mfma_f32_32x32x16_bf16(a0s, b0, aS, 0, 0, 0);
      aS = __builtin_amdgcn_mfma_f32_32x32x16_bf16(a1s, b1, aS, 0, 0, 0);
    }

    // ---- gated activation -> zl ----
#pragma unroll
    for (int r = 0; r < 16; r += 2) {
      int ic0 = (r & 3) + 4 * hi + 8 * (r >> 2) + 32 * pr;
      float z0 = (1.f - 2.f / (__expf(2.f * aA[r]) + 1.f)) *
                 (1.f / (1.f + __expf(-aS[r])));
      float z1 = (1.f - 2.f / (__expf(2.f * aA[r + 1]) + 1.f)) *
                 (1.f / (1.f + __expf(-aS[r + 1])));
      unsigned int v = (unsigned int)bf16_rn(z0) | ((unsigned int)bf16_rn(z1) << 16);
      int p = (ic0 & ~15) | kpos(ic0 & 15);
      unsigned int byte = (unsigned int)(tloc * 128 + p * 2) ^ (unsigned int)((tloc & 7) << 4);
      *(unsigned int*)((char*)zl + byte) = v;
    }
    __syncthreads();

    // ---- skip accumulation: s[mt][sk=wv*32+l31] += z @ wsk_i^T ----
    {
      const short* wb = wsk + (size_t)i * 16384 + (wv * 32 + l31) * 64;
#define SKIP_MT(SS, MT)                                                        \
  {                                                                            \
    const int trow = (MT)*32 + l31;                                            \
    _Pragma("unroll") for (int ks = 0; ks < 4; ++ks) {                         \
      int off = ks * 16 + 8 * hi;                                              \
      short8 bw = *(const short8*)(wb + off);                                  \
      short8 az = *(const short8*)((char*)zl +                                 \
          ((unsigned int)(trow * 128 + off * 2) ^                              \
           (unsigned int)((trow & 7) << 4)));                                  \
      SS = __builtin_amdgcn_mfma_f32_32x32x16_bf16(az, bw, SS, 0, 0, 0);       \
    }                                                                          \
  }
      SKIP_MT(s0, 0) SKIP_MT(s1, 1) SKIP_MT(s2, 2) SKIP_MT(s3, 3)
#undef SKIP_MT
    }

    if (i < NB - 1) {
      // ---- residual: rs += z @ wres^T (D[row=t][col=oc]) ----
      const int mt = wv >> 1, ntr = wv & 1;
      const int trow = mt * 32 + l31;
      f32x16 ar = {};
      const short* wrb = wr + (size_t)i * 4096 + (ntr * 32 + l31) * 64;
#pragma unroll
      for (int ks = 0; ks < 4; ++ks) {
        int off = ks * 16 + 8 * hi;
        short8 az = *(const short8*)((char*)zl +
            ((unsigned int)(trow * 128 + off * 2) ^ (unsigned int)((trow & 7) << 4)));
        short8 bw = *(const short8*)(wrb + off);
        ar = __builtin_amdgcn_mfma_f32_32x32x16_bf16(az, bw, ar, 0, 0, 0);
      }
#pragma unroll
      for (int r = 0; r < 16; ++r) {
        int t = mt * 32 + (r & 3) + 4 * hi + 8 * (r >> 2);
        int oc = ntr * 32 + l31;
        rs[t * 64 + oc] += ar[r];
      }
      __syncthreads();  // rs update visible before publish

      // ---- publish tail rows needed by next block's halo ----
      const int nd = 1 << ((i + 1) & 7);
      const int nwr = nd < 128 ? nd : 128;
      unsigned short* wbuf = bufs[(i + 1) & 1];
      for (int u = tid; u < nwr * 32; u += 512) {
        int cpair = u & 31, row = 128 - nwr + (u >> 5);
        int c0 = cpair * 2;
        unsigned int v = (unsigned int)bf16_rn(rs[row * 64 + c0]) |
                         ((unsigned int)bf16_rn(rs[row * 64 + c0 + 1]) << 16);
        int p0 = (c0 & 48) | kpos(c0 & 15);
        *(unsigned int*)(wbuf + ((size_t)b * TT + t0 + row) * 64 + p0) = v;
      }
      grid_bar(bar, i + 1);
    }
  }

  // ================= head (same WG, LDS reused) =================
  __syncthreads();

  // relu(skip) -> yb [128][256] k-permuted swizzled
  {
    int sk = wv * 32 + l31;
    int p = (sk & 0xF0) | kpos(sk & 15);
#define RELU_MT(SS, MT)                                                        \
  {                                                                            \
    _Pragma("unroll") for (int r = 0; r < 16; ++r) {                           \
      int dt = (MT)*32 + (r & 3) + 4 * hi + 8 * (r >> 2);                      \
      unsigned int byte =                                                      \
          (unsigned int)(dt * 512 + p * 2) ^ (unsigned int)((dt & 7) << 4);    \
      *(short*)((char*)yb + byte) = (short)bf16_rn(fmaxf(SS[r], 0.f));         \
    }                                                                          \
  }
    RELU_MT(s0, 0) RELU_MT(s1, 1) RELU_MT(s2, 2) RELU_MT(s3, 3)
#undef RELU_MT
  }
  __syncthreads();

  // y2 = relu(w1 @ y): D[row=o][col=t] -> y2b transposed [t][op]
  {
    const short* w1r = w1 + (wv * 32 + l31) * 256;
#pragma unroll
    for (int ntile = 0; ntile < 4; ++ntile) {
      const int trow = ntile * 32 + l31;
      f32x16 acc = {};
#pragma unroll
      for (int ks = 0; ks < 16; ++ks) {
        int off = ks * 16 + 8 * hi;
        short8 by = *(const short8*)((char*)yb +
            ((unsigned int)(trow * 512 + off * 2) ^ (unsigned int)((trow & 7) << 4)));
        short8 aw = *(const short8*)(w1r + off);
        acc = __builtin_amdgcn_mfma_f32_32x32x16_bf16(aw, by, acc, 0, 0, 0);
      }
#pragma unroll
      for (int r = 0; r < 16; r += 2) {
        int o0 = wv * 32 + (r & 3) + 4 * hi + 8 * (r >> 2);
        unsigned int v = (unsigned int)bf16_rn(fmaxf(acc[r], 0.f)) |
                         ((unsigned int)bf16_rn(fmaxf(acc[r + 1], 0.f)) << 16);
        int p = (o0 & 0xF0) | kpos(o0 & 15);
        unsigned int byte = (unsigned int)(trow * 512 + p * 2) ^ (unsigned int)((trow & 7) << 4);
        *(unsigned int*)((char*)y2b + byte) = v;
      }
    }
  }
  __syncthreads();

  // out = w2 @ y2: D[row=oc][col=t], coalesced [B][OUT][T] write
  {
    const short* w2r = w2 + (wv * 32 + l31) * 256;
    float* ob = out + (size_t)b * 256 * TT;
#pragma unroll
    for (int ntile = 0; ntile < 4; ++ntile) {
      const int trow = ntile * 32 + l31;
      f32x16 acc = {};
#pragma unroll
      for (int ks = 0; ks < 16; ++ks) {
        int off = ks * 16 + 8 * hi;
        short8 by = *(const short8*)((char*)y2b +
            ((unsigned int)(trow * 512 + off * 2) ^ (unsigned int)((trow & 7) << 4)));
        short8 aw = *(const short8*)(w2r + off);
        acc = __builtin_amdgcn_mfma_f32_32x32x16_bf16(aw, by, acc, 0, 0, 0);
      }
#pragma unroll
      for (int r = 0; r < 16; ++r) {
        int oc = wv * 32 + (r & 3) + 4 * hi + 8 * (r >> 2);
        ob[(size_t)oc * TT + t0 + trow] = acc[r];
      }
    }
  }
}

// ---------------------------------------------------------------------------
extern "C" void kernel_launch(void* const* d_in, const int* in_sizes, int n_in,
                              void* d_out, int out_size, void* d_ws, size_t ws_size,
                              hipStream_t stream)
{
  const int* x = (const int*)d_in[0];
  const float* h = (const float*)d_in[1];
  const float* embed = (const float*)d_in[2];
  const float* w_conv = (const float*)d_in[3];
  const float* w_res = (const float*)d_in[4];
  const float* w_skip = (const float*)d_in[5];
  const float* w_out1 = (const float*)d_in[6];
  const float* w_out2 = (const float*)d_in[7];
  float* out = (float*)d_out;

  char* ws = (char*)d_ws;
  unsigned short* r16a = (unsigned short*)ws;                        // 4 MB
  unsigned short* r16b = (unsigned short*)(ws + (size_t)(4 << 20));  // 4 MB
  short* dwc = (short*)(ws + (size_t)(8 << 20));                     // 512 KB
  short* dwr = dwc + 262144;
  short* dws = dwr + 65536;
  short* dw1 = dws + 262144;
  short* dw2 = dw1 + 65536;
  unsigned* bar = (unsigned*)(ws + (size_t)(10 << 20));              // 64 ctrs

  hipMemsetAsync(bar, 0, 64 * sizeof(unsigned), stream);
  prep_weights<<<2816, 256, 0, stream>>>(w_conv, w_res, w_skip, w_out1, w_out2,
                                         dwc, dwr, dws, dw1, dw2);
  mega_kernel<<<dim3(TT / 128, Bb), 512, 0, stream>>>(
      x, h, embed, dwc, dwr, dws, dw1, dw2, r16a, r16b, bar, out);
}